// Round 1
// baseline (181.926 us; speedup 1.0000x reference)
//
#include <hip/hip_runtime.h>

#define POOLK 7
#define NBINS 49            // POOLK*POOLK
#define ALPHA 32
#define C4N   8             // ALPHA/4
#define HH    128
#define WW    128
#define NUM_ROIS 4096

// img:  (1, 128, 128, 1568) f32  -> viewed as feat (128,128,49,32)
// rois: (1, 4096, 4) f32         -> (xmin, ymin, xmax, ymax)
// out:  (1, 4096, 7, 7, 32) f32  -> flat: roi*1568 + g*32 + c, g = p*7+q
__global__ __launch_bounds__(256) void psroi_align_kernel(
    const float* __restrict__ img,
    const float* __restrict__ rois,
    float* __restrict__ out)
{
    const int tid = blockIdx.x * blockDim.x + threadIdx.x;
    const int c4  = tid & (C4N - 1);       // which float4 of the 32 channels
    const int rg  = tid >> 3;              // roi*49 + g
    if (rg >= NUM_ROIS * NBINS) return;
    const int g   = rg % NBINS;
    const int roi = rg / NBINS;

    const float xmin = rois[roi * 4 + 0];
    const float ymin = rois[roi * 4 + 1];
    const float xmax = rois[roi * 4 + 2];
    const float ymax = rois[roi * 4 + 3];

    const float step_y = (ymax - ymin) * (1.0f / POOLK);
    const float step_x = (xmax - xmin) * (1.0f / POOLK);

    const int p = g / POOLK;               // bx = g // 7  (x bin)
    const int q = g % POOLK;               // by = g % 7   (y bin)

    const float y1 = ymin + (float)q * step_y;
    const float x1 = xmin + (float)p * step_x;
    const float y2 = y1 + step_y;
    const float x2 = x1 + step_x;

    const float scale = (float)(HH - 1);   // 127, H==W
    // t = {0, 1}: sample at (y1 + (y2-y1)*t) * 127
    float ysamp[2], xsamp[2];
    ysamp[0] = y1 * scale;
    ysamp[1] = (y1 + (y2 - y1)) * scale;
    xsamp[0] = x1 * scale;
    xsamp[1] = (x1 + (x2 - x1)) * scale;

    const float4* __restrict__ feat = (const float4*)img;
    // feat4 index: ((y*128 + x)*49 + g)*8 + c4
    const int gbase = g * C4N + c4;

    float4 vmax;
    vmax.x = -INFINITY; vmax.y = -INFINITY; vmax.z = -INFINITY; vmax.w = -INFINITY;

    #pragma unroll
    for (int sy = 0; sy < 2; ++sy) {
        const float yg  = ysamp[sy];
        const bool  vy  = (yg >= 0.0f) && (yg <= (float)(HH - 1));
        const float y0f = floorf(yg);
        const float wy  = yg - y0f;
        int y0 = (int)y0f;
        y0 = min(max(y0, 0), HH - 1);
        const int y1i = min(y0 + 1, HH - 1);

        #pragma unroll
        for (int sx = 0; sx < 2; ++sx) {
            const float xg  = xsamp[sx];
            const bool  vx  = (xg >= 0.0f) && (xg <= (float)(WW - 1));
            const float x0f = floorf(xg);
            const float wx  = xg - x0f;
            int x0 = (int)x0f;
            x0 = min(max(x0, 0), WW - 1);
            const int x1i = min(x0 + 1, WW - 1);

            const float w00 = (1.0f - wy) * (1.0f - wx);
            const float w01 = (1.0f - wy) * wx;
            const float w10 = wy * (1.0f - wx);
            const float w11 = wy * wx;

            const float4 v00 = feat[(y0  * WW + x0 ) * NBINS * C4N + gbase];
            const float4 v01 = feat[(y0  * WW + x1i) * NBINS * C4N + gbase];
            const float4 v10 = feat[(y1i * WW + x0 ) * NBINS * C4N + gbase];
            const float4 v11 = feat[(y1i * WW + x1i) * NBINS * C4N + gbase];

            float4 v;
            v.x = v00.x * w00 + v01.x * w01 + v10.x * w10 + v11.x * w11;
            v.y = v00.y * w00 + v01.y * w01 + v10.y * w10 + v11.y * w11;
            v.z = v00.z * w00 + v01.z * w01 + v10.z * w10 + v11.z * w11;
            v.w = v00.w * w00 + v01.w * w01 + v10.w * w10 + v11.w * w11;

            const bool valid = vy && vx;
            if (!valid) { v.x = 0.0f; v.y = 0.0f; v.z = 0.0f; v.w = 0.0f; }

            vmax.x = fmaxf(vmax.x, v.x);
            vmax.y = fmaxf(vmax.y, v.y);
            vmax.z = fmaxf(vmax.z, v.z);
            vmax.w = fmaxf(vmax.w, v.w);
        }
    }

    float4* __restrict__ out4 = (float4*)out;
    out4[rg * C4N + c4] = vmax;
}

extern "C" void kernel_launch(void* const* d_in, const int* in_sizes, int n_in,
                              void* d_out, int out_size, void* d_ws, size_t ws_size,
                              hipStream_t stream) {
    const float* img  = (const float*)d_in[0];
    const float* rois = (const float*)d_in[1];
    float* out = (float*)d_out;

    const int total_threads = NUM_ROIS * NBINS * C4N;   // 1,605,632
    const int block = 256;
    const int grid  = (total_threads + block - 1) / block;  // 6272
    psroi_align_kernel<<<grid, block, 0, stream>>>(img, rois, out);
}